// Round 1
// baseline (16471.103 us; speedup 1.0000x reference)
//
#include <hip/hip_runtime.h>
#include <hip/hip_bf16.h>

// Problem constants: B=8, N=4096 (=64x64 spatial), C=768, H=12, hd=64.
// Y = ReFFT2_spatial(X) @ (proj_w @ Wv)^T + proj_b, Wv = qkv_w[1536:2304].

typedef __bf16 bf16x8 __attribute__((ext_vector_type(8)));
typedef float f32x4 __attribute__((ext_vector_type(4)));

typedef __attribute__((address_space(3))) unsigned int lds_u32;
typedef __attribute__((address_space(1))) unsigned int glob_u32;

__device__ __forceinline__ void gl_lds16(const void* g, void* l) {
  // async global->LDS, 16B per lane, LDS dest = wave-uniform base + lane*16
  __builtin_amdgcn_global_load_lds((const glob_u32*)g, (lds_u32*)l, 16, 0, 0);
}

// ---------- compile-time trig: cos/sin(2*pi*m/64) as folded constants ----------
constexpr double ccos_taylor(double x) {  // |x| <= pi/2
  double x2 = x * x, term = 1.0, s = 1.0;
  for (int k = 1; k <= 10; ++k) { term *= -x2 / ((2.0 * k - 1.0) * (2.0 * k)); s += term; }
  return s;
}
constexpr float COS64(int m) {
  m &= 63;
  double sg = 1.0;
  if (m > 32) m = 64 - m;
  if (m > 16) { m = 32 - m; sg = -1.0; }
  return (float)(sg * ccos_taylor(m * 0.09817477042468103870195760572748));  // pi/32
}
constexpr float SIN64(int m) { return COS64(m - 16); }  // sin(t) = cos(t - pi/2)

// ---------- K1: M[i,c] = sum_d proj_w[i,d] * qkv_w[1536+d, c]  (fp32 -> bf16) ----------
__global__ __launch_bounds__(256) void precompute_m(const float* __restrict__ P,
                                                    const float* __restrict__ Q,
                                                    __hip_bfloat16* __restrict__ Mb) {
  __shared__ float Pt[32][33], Qt[32][33];
  const int t = threadIdx.x;
  const int i0 = blockIdx.y * 32, c0 = blockIdx.x * 32;
  const int ty = t >> 4, tx = t & 15;
  float acc[2][2] = {};
  for (int kt = 0; kt < 24; ++kt) {
    const int k0 = kt * 32;
#pragma unroll
    for (int it = 0; it < 4; ++it) {
      int e = it * 256 + t, r = e >> 5, c = e & 31;
      Pt[r][c] = P[(size_t)(i0 + r) * 768 + k0 + c];
      Qt[r][c] = Q[(size_t)(1536 + k0 + r) * 768 + c0 + c];
    }
    __syncthreads();
#pragma unroll
    for (int k = 0; k < 32; ++k) {
      float a0 = Pt[ty * 2][k], a1 = Pt[ty * 2 + 1][k];
      float b0 = Qt[k][tx * 2], b1 = Qt[k][tx * 2 + 1];
      acc[0][0] = fmaf(a0, b0, acc[0][0]);
      acc[0][1] = fmaf(a0, b1, acc[0][1]);
      acc[1][0] = fmaf(a1, b0, acc[1][0]);
      acc[1][1] = fmaf(a1, b1, acc[1][1]);
    }
    __syncthreads();
  }
#pragma unroll
  for (int a = 0; a < 2; ++a)
#pragma unroll
    for (int b = 0; b < 2; ++b)
      Mb[(size_t)(i0 + ty * 2 + a) * 768 + c0 + tx * 2 + b] = __float2bfloat16(acc[a][b]);
}

// ---------- K2: pass A, contract n2: Ar/Ai[b,n1,k2,c] ----------
template <int HALF>
__global__ __launch_bounds__(128) void fft_a(const float* __restrict__ X,
                                             __hip_bfloat16* __restrict__ Ar,
                                             __hip_bfloat16* __restrict__ Ai) {
  __shared__ float Xt[64 * 128];
  const int t = threadIdx.x;
  const int b = blockIdx.z, n1 = blockIdx.y, c0 = blockIdx.x * 128;
  const float* src = X + (size_t)(b * 4096 + n1 * 64) * 768 + c0;
#pragma unroll
  for (int it = 0; it < 16; ++it) {
    int e = it * 512 + t * 4, row = e >> 7, col = e & 127;
    *(float4*)&Xt[e] = *(const float4*)&src[(size_t)row * 768 + col];
  }
  __syncthreads();
  float v[64];
#pragma unroll
  for (int n2 = 0; n2 < 64; ++n2) v[n2] = Xt[n2 * 128 + t];
  const size_t obase = (size_t)(b * 64 + n1) * 64 * 768 + c0 + t;
#pragma unroll
  for (int j = 0; j < 32; ++j) {
    const int k2 = HALF * 32 + j;
    float ar = 0.f, ai = 0.f;
#pragma unroll
    for (int n2 = 0; n2 < 64; ++n2) {
      ar = fmaf(COS64(n2 * k2), v[n2], ar);
      ai = fmaf(SIN64(n2 * k2), v[n2], ai);
    }
    Ar[obase + (size_t)k2 * 768] = __float2bfloat16(ar);
    Ai[obase + (size_t)k2 * 768] = __float2bfloat16(ai);
  }
}

// ---------- K3: pass B, contract n1: Xf[b, k1*64+k2, c] = sum cos*Ar - sin*Ai ----------
template <int HALF>
__global__ __launch_bounds__(128) void fft_b(const __hip_bfloat16* __restrict__ Ar,
                                             const __hip_bfloat16* __restrict__ Ai,
                                             __hip_bfloat16* __restrict__ Xf) {
  __shared__ __hip_bfloat16 Rt[64 * 128];
  __shared__ __hip_bfloat16 It[64 * 128];
  const int t = threadIdx.x;
  const int b = blockIdx.z, k2 = blockIdx.y, c0 = blockIdx.x * 128;
  const size_t rbase = ((size_t)(b * 64) * 64 + k2) * 768 + c0;  // + n1 * 64*768
#pragma unroll
  for (int it = 0; it < 8; ++it) {
    int e = it * 1024 + t * 8, row = e >> 7, col = e & 127;
    size_t g = rbase + (size_t)row * 64 * 768 + col;
    *(uint4*)&Rt[e] = *(const uint4*)&Ar[g];
    *(uint4*)&It[e] = *(const uint4*)&Ai[g];
  }
  __syncthreads();
  float vr[64], vi[64];
#pragma unroll
  for (int n1 = 0; n1 < 64; ++n1) {
    vr[n1] = __bfloat162float(Rt[n1 * 128 + t]);
    vi[n1] = __bfloat162float(It[n1 * 128 + t]);
  }
  const size_t obase = ((size_t)b * 4096 + k2) * 768 + c0 + t;  // + k1 * 64*768
#pragma unroll
  for (int j = 0; j < 32; ++j) {
    const int k1 = HALF * 32 + j;
    float acc = 0.f;
#pragma unroll
    for (int n1 = 0; n1 < 64; ++n1) {
      acc = fmaf(COS64(n1 * k1), vr[n1], acc);
      acc = fmaf(-SIN64(n1 * k1), vi[n1], acc);
    }
    Xf[obase + (size_t)k1 * 64 * 768] = __float2bfloat16(acc);
  }
}

// ---------- K4: Y[m,n] = sum_k Xf[m,k]*Mb[n,k] + bias[n]  (bf16 MFMA, fp32 out) ----------
// M=32768, N=768, K=768. 128x128 tile, BK=32, 4 waves (2x2), 4x4 16x16x32 MFMAs/wave.
__global__ __launch_bounds__(256) void gemm_bt(const __hip_bfloat16* __restrict__ A,
                                               const __hip_bfloat16* __restrict__ B,
                                               const float* __restrict__ bias,
                                               float* __restrict__ C) {
  __shared__ __hip_bfloat16 As[128 * 32];
  __shared__ __hip_bfloat16 Bs[128 * 32];
  const int t = threadIdx.x, w = t >> 6, l = t & 63;
  const int n0 = blockIdx.x * 128, m0 = blockIdx.y * 128;
  const int wm = w & 1, wn = w >> 1;
  f32x4 acc[4][4] = {};
  const int srow_b = (l >> 2);      // + (w*2+j)*16
  const int scol = (l & 3) * 8;
  for (int kt = 0; kt < 24; ++kt) {
    const int k0 = kt * 32;
#pragma unroll
    for (int j = 0; j < 2; ++j) {
      const int ldso = (w * 2 + j) * 512;               // wave-uniform LDS elem offset
      const int row = (w * 2 + j) * 16 + srow_b;
      gl_lds16(&A[(size_t)(m0 + row) * 768 + k0 + scol], &As[ldso]);
      gl_lds16(&B[(size_t)(n0 + row) * 768 + k0 + scol], &Bs[ldso]);
    }
    __syncthreads();
    bf16x8 af[4], bfr[4];
#pragma unroll
    for (int mt = 0; mt < 4; ++mt)
      af[mt] = *(const bf16x8*)&As[(wm * 64 + mt * 16 + (l & 15)) * 32 + (l >> 4) * 8];
#pragma unroll
    for (int nt = 0; nt < 4; ++nt)
      bfr[nt] = *(const bf16x8*)&Bs[(wn * 64 + nt * 16 + (l & 15)) * 32 + (l >> 4) * 8];
#pragma unroll
    for (int mt = 0; mt < 4; ++mt)
#pragma unroll
      for (int nt = 0; nt < 4; ++nt)
        acc[mt][nt] = __builtin_amdgcn_mfma_f32_16x16x32_bf16(af[mt], bfr[nt], acc[mt][nt], 0, 0, 0);
    __syncthreads();
  }
#pragma unroll
  for (int nt = 0; nt < 4; ++nt) {
    const int col = n0 + wn * 64 + nt * 16 + (l & 15);
    const float bv = bias[col];
#pragma unroll
    for (int mt = 0; mt < 4; ++mt) {
      const int rbase = m0 + wm * 64 + mt * 16 + (l >> 4) * 4;
#pragma unroll
      for (int r = 0; r < 4; ++r)
        C[(size_t)(rbase + r) * 768 + col] = acc[mt][nt][r] + bv;
    }
  }
}

extern "C" void kernel_launch(void* const* d_in, const int* in_sizes, int n_in,
                              void* d_out, int out_size, void* d_ws, size_t ws_size,
                              hipStream_t stream) {
  const float* x      = (const float*)d_in[0];  // [8,4096,768]
  const float* qkv_w  = (const float*)d_in[1];  // [2304,768]
  const float* proj_w = (const float*)d_in[2];  // [768,768]
  const float* proj_b = (const float*)d_in[3];  // [768]
  float* out = (float*)d_out;                   // [8,4096,768] fp32

  char* ws = (char*)d_ws;
  const size_t MB_BYTES = (size_t)768 * 768 * 2;          // 1,179,648
  const size_t ARR_BYTES = (size_t)8 * 4096 * 768 * 2;    // 50,331,648
  __hip_bfloat16* Mb = (__hip_bfloat16*)ws;
  __hip_bfloat16* Ar = (__hip_bfloat16*)(ws + MB_BYTES);
  __hip_bfloat16* Ai = (__hip_bfloat16*)(ws + MB_BYTES + ARR_BYTES);
  __hip_bfloat16* Xf = (__hip_bfloat16*)(ws + MB_BYTES + 2 * ARR_BYTES);
  // total ws use: 152,174,592 bytes

  precompute_m<<<dim3(24, 24), 256, 0, stream>>>(proj_w, qkv_w, Mb);
  fft_a<0><<<dim3(6, 64, 8), 128, 0, stream>>>(x, Ar, Ai);
  fft_a<1><<<dim3(6, 64, 8), 128, 0, stream>>>(x, Ar, Ai);
  fft_b<0><<<dim3(6, 64, 8), 128, 0, stream>>>(Ar, Ai, Xf);
  fft_b<1><<<dim3(6, 64, 8), 128, 0, stream>>>(Ar, Ai, Xf);
  gemm_bt<<<dim3(6, 256), 256, 0, stream>>>(Xf, Mb, proj_b, out);
}

// Round 2
// 327.879 us; speedup vs baseline: 50.2354x; 50.2354x over previous
//
#include <hip/hip_runtime.h>
#include <hip/hip_bf16.h>

// B=8, N=4096 (=64x64 spatial), C=768.
// Y = ReFFT2_spatial(X) @ (proj_w @ Wv)^T + proj_b,  Wv = qkv_w[1536:2304].
// ReFFT2 = C V C - S V S done as two MFMA passes with twiddle ops fused.

typedef __bf16 bf16x8 __attribute__((ext_vector_type(8)));
typedef __bf16 bf16x4 __attribute__((ext_vector_type(4)));
typedef float f32x4 __attribute__((ext_vector_type(4)));
typedef unsigned short ushort_t;
typedef unsigned int uint_t;

typedef __attribute__((address_space(3))) unsigned int lds_u32;
typedef __attribute__((address_space(1))) unsigned int glob_u32;

__device__ __forceinline__ void gl_lds16(const void* g, void* l) {
  __builtin_amdgcn_global_load_lds((const glob_u32*)g, (lds_u32*)l, 16, 0, 0);
}

__device__ __forceinline__ ushort_t f2bf(float f) {
  union { __hip_bfloat16 h; ushort_t s; } cv;
  cv.h = __float2bfloat16(f);
  return cv.s;
}

// bf16x8 fragment load from LDS at 8-byte-aligned address (two b64 reads)
__device__ __forceinline__ bf16x8 ld_frag(const ushort_t* p) {
  union { bf16x8 v; bf16x4 h[2]; } r;
  r.h[0] = *(const bf16x4*)p;
  r.h[1] = *(const bf16x4*)(p + 4);
  return r.v;
}

// Twiddle A-fragment: val[j] = sign * trig(2*pi*(m*(k0+j) mod 64)/64), bf16-packed.
__device__ __forceinline__ bf16x8 tw_frag(int m, int k0, bool use_sin, float sign) {
  union { bf16x8 v; ushort_t u[8]; } r;
#pragma unroll
  for (int j = 0; j < 8; ++j) {
    int ph = (m * (k0 + j)) & 63;
    float a = (float)ph * 0.09817477042468104f;  // 2*pi/64
    float x = use_sin ? __sinf(a) : __cosf(a);
    r.u[j] = f2bf(sign * x);
  }
  return r.v;
}

// ---------- K1: M[i,c] = sum_d proj_w[i,d] * qkv_w[1536+d, c]  (fp32 -> bf16) ----------
__global__ __launch_bounds__(256) void precompute_m(const float* __restrict__ P,
                                                    const float* __restrict__ Q,
                                                    __hip_bfloat16* __restrict__ Mb) {
  __shared__ float Pt[32][33], Qt[32][33];
  const int t = threadIdx.x;
  const int i0 = blockIdx.y * 32, c0 = blockIdx.x * 32;
  const int ty = t >> 4, tx = t & 15;
  float acc[2][2] = {};
  for (int kt = 0; kt < 24; ++kt) {
    const int k0 = kt * 32;
#pragma unroll
    for (int it = 0; it < 4; ++it) {
      int e = it * 256 + t, r = e >> 5, c = e & 31;
      Pt[r][c] = P[(size_t)(i0 + r) * 768 + k0 + c];
      Qt[r][c] = Q[(size_t)(1536 + k0 + r) * 768 + c0 + c];
    }
    __syncthreads();
#pragma unroll
    for (int k = 0; k < 32; ++k) {
      float a0 = Pt[ty * 2][k], a1 = Pt[ty * 2 + 1][k];
      float b0 = Qt[k][tx * 2], b1 = Qt[k][tx * 2 + 1];
      acc[0][0] = fmaf(a0, b0, acc[0][0]);
      acc[0][1] = fmaf(a0, b1, acc[0][1]);
      acc[1][0] = fmaf(a1, b0, acc[1][0]);
      acc[1][1] = fmaf(a1, b1, acc[1][1]);
    }
    __syncthreads();
  }
#pragma unroll
  for (int a = 0; a < 2; ++a)
#pragma unroll
    for (int b = 0; b < 2; ++b)
      Mb[(size_t)(i0 + ty * 2 + a) * 768 + c0 + tx * 2 + b] = __float2bfloat16(acc[a][b]);
}

// ---------- K2: pass A (MFMA), contract n2.  Out: Ar/Ai[(b*64+n1)*64 + k2][768] ----------
// Block: 256 thr (4 waves), one (b,n1) slab x 128-c tile. D[k2=64][c=128].
__global__ __launch_bounds__(256) void fft_a_mfma(const float* __restrict__ X,
                                                  __hip_bfloat16* __restrict__ Ar,
                                                  __hip_bfloat16* __restrict__ Ai) {
  __shared__ ushort_t Xs[128 * 68];   // [c][n2], stride 68 bf16
  __shared__ ushort_t Ep[64 * 136];   // epilogue transpose [k2][c], stride 136
  const int t = threadIdx.x;
  const int s = blockIdx.y;           // b*64 + n1
  const int c0 = blockIdx.x * 128;
  const float* src = X + (size_t)s * 64 * 768 + c0;
  // stage: global [n2][c] fp32 -> LDS [c][n2] bf16 (pairs along n2 -> b32 writes)
#pragma unroll
  for (int it = 0; it < 16; ++it) {
    int p = it * 256 + t;
    int c = p & 127, pr = p >> 7;     // pr = n2 pair 0..31
    float a = src[(size_t)(2 * pr) * 768 + c];
    float b = src[(size_t)(2 * pr + 1) * 768 + c];
    union { ushort_t u[2]; uint_t w; } pk;
    pk.u[0] = f2bf(a); pk.u[1] = f2bf(b);
    *(uint_t*)&Xs[c * 68 + 2 * pr] = pk.w;
  }
  __syncthreads();
  const int w = t >> 6, l = t & 63;
  const int wm = w & 1, wn = w >> 1;
  const int lm = l & 15, lq = l >> 4;
  bf16x8 afc[2][2], afs[2][2];
#pragma unroll
  for (int mt = 0; mt < 2; ++mt)
#pragma unroll
    for (int ks = 0; ks < 2; ++ks) {
      int m = wm * 32 + mt * 16 + lm;
      int k0 = ks * 32 + lq * 8;
      afc[mt][ks] = tw_frag(m, k0, false, 1.f);
      afs[mt][ks] = tw_frag(m, k0, true, 1.f);
    }
  f32x4 accr[2][4] = {}, acci[2][4] = {};
#pragma unroll
  for (int ks = 0; ks < 2; ++ks) {
    bf16x8 bf[4];
#pragma unroll
    for (int nt = 0; nt < 4; ++nt) {
      int c = wn * 64 + nt * 16 + lm;
      int kb = ks * 32 + lq * 8;
      bf[nt] = ld_frag(&Xs[c * 68 + kb]);
    }
#pragma unroll
    for (int mt = 0; mt < 2; ++mt)
#pragma unroll
      for (int nt = 0; nt < 4; ++nt) {
        accr[mt][nt] = __builtin_amdgcn_mfma_f32_16x16x32_bf16(afc[mt][ks], bf[nt], accr[mt][nt], 0, 0, 0);
        acci[mt][nt] = __builtin_amdgcn_mfma_f32_16x16x32_bf16(afs[mt][ks], bf[nt], acci[mt][nt], 0, 0, 0);
      }
  }
  // epilogue: R then I through LDS transpose -> coalesced 16B stores
#pragma unroll
  for (int arr = 0; arr < 2; ++arr) {
    __syncthreads();
#pragma unroll
    for (int mt = 0; mt < 2; ++mt)
#pragma unroll
      for (int nt = 0; nt < 4; ++nt)
#pragma unroll
        for (int r = 0; r < 4; ++r) {
          int row = wm * 32 + mt * 16 + lq * 4 + r;
          int col = wn * 64 + nt * 16 + lm;
          float v = arr ? acci[mt][nt][r] : accr[mt][nt][r];
          Ep[row * 136 + col] = f2bf(v);
        }
    __syncthreads();
    __hip_bfloat16* dst = arr ? Ai : Ar;
#pragma unroll
    for (int it = 0; it < 4; ++it) {
      int idx = it * 256 + t;         // 1024 x uint4
      int row = idx >> 4, cq = (idx & 15) * 8;
      uint4 v = *(const uint4*)&Ep[row * 136 + cq];
      *(uint4*)&dst[(size_t)(s * 64 + row) * 768 + c0 + cq] = v;
    }
  }
}

// ---------- K3: pass B (MFMA), contract n1.  Out: Xf[b*4096 + k1*64 + k2][768] ----------
__global__ __launch_bounds__(256) void fft_b_mfma(const __hip_bfloat16* __restrict__ Ar,
                                                  const __hip_bfloat16* __restrict__ Ai,
                                                  __hip_bfloat16* __restrict__ Xf) {
  __shared__ ushort_t Rs[128 * 68], Is[128 * 68];
  __shared__ ushort_t Ep[64 * 136];
  const int t = threadIdx.x;
  const int bz = blockIdx.y;          // b*64 + k2
  const int b = bz >> 6, k2 = bz & 63;
  const int c0 = blockIdx.x * 128;
  const ushort_t* ar = (const ushort_t*)Ar + ((size_t)(b * 64) * 64 + k2) * 768 + c0;
  const ushort_t* ai = (const ushort_t*)Ai + ((size_t)(b * 64) * 64 + k2) * 768 + c0;
  const size_t n1s = (size_t)64 * 768;
#pragma unroll
  for (int it = 0; it < 16; ++it) {
    int p = it * 256 + t;
    int c = p & 127, pr = p >> 7;
    size_t o0 = (size_t)(2 * pr) * n1s + c;
    size_t o1 = o0 + n1s;
    union { ushort_t u[2]; uint_t w; } p1, p2;
    p1.u[0] = ar[o0]; p1.u[1] = ar[o1];
    p2.u[0] = ai[o0]; p2.u[1] = ai[o1];
    *(uint_t*)&Rs[c * 68 + 2 * pr] = p1.w;
    *(uint_t*)&Is[c * 68 + 2 * pr] = p2.w;
  }
  __syncthreads();
  const int w = t >> 6, l = t & 63;
  const int wm = w & 1, wn = w >> 1;
  const int lm = l & 15, lq = l >> 4;
  bf16x8 afc[2][2], afn[2][2];
#pragma unroll
  for (int mt = 0; mt < 2; ++mt)
#pragma unroll
    for (int ks = 0; ks < 2; ++ks) {
      int m = wm * 32 + mt * 16 + lm;   // m = k1
      int k0 = ks * 32 + lq * 8;        // k = n1
      afc[mt][ks] = tw_frag(m, k0, false, 1.f);
      afn[mt][ks] = tw_frag(m, k0, true, -1.f);   // -sin
    }
  f32x4 acc[2][4] = {};
#pragma unroll
  for (int ks = 0; ks < 2; ++ks) {
    bf16x8 bR[4], bI[4];
#pragma unroll
    for (int nt = 0; nt < 4; ++nt) {
      int c = wn * 64 + nt * 16 + lm;
      int kb = ks * 32 + lq * 8;
      bR[nt] = ld_frag(&Rs[c * 68 + kb]);
      bI[nt] = ld_frag(&Is[c * 68 + kb]);
    }
#pragma unroll
    for (int mt = 0; mt < 2; ++mt)
#pragma unroll
      for (int nt = 0; nt < 4; ++nt) {
        acc[mt][nt] = __builtin_amdgcn_mfma_f32_16x16x32_bf16(afc[mt][ks], bR[nt], acc[mt][nt], 0, 0, 0);
        acc[mt][nt] = __builtin_amdgcn_mfma_f32_16x16x32_bf16(afn[mt][ks], bI[nt], acc[mt][nt], 0, 0, 0);
      }
  }
#pragma unroll
  for (int mt = 0; mt < 2; ++mt)
#pragma unroll
    for (int nt = 0; nt < 4; ++nt)
#pragma unroll
      for (int r = 0; r < 4; ++r) {
        int row = wm * 32 + mt * 16 + lq * 4 + r;   // k1
        int col = wn * 64 + nt * 16 + lm;           // c
        Ep[row * 136 + col] = f2bf(acc[mt][nt][r]);
      }
  __syncthreads();
#pragma unroll
  for (int it = 0; it < 4; ++it) {
    int idx = it * 256 + t;
    int k1 = idx >> 4, cq = (idx & 15) * 8;
    uint4 v = *(const uint4*)&Ep[k1 * 136 + cq];
    *(uint4*)&Xf[((size_t)b * 4096 + k1 * 64 + k2) * 768 + c0 + cq] = v;
  }
}

// ---------- K4: Y[m,n] = sum_k Xf[m,k]*Mb[n,k] + bias[n]  (bf16 MFMA, fp32 out) ----------
__global__ __launch_bounds__(256) void gemm_bt(const __hip_bfloat16* __restrict__ A,
                                               const __hip_bfloat16* __restrict__ B,
                                               const float* __restrict__ bias,
                                               float* __restrict__ C) {
  __shared__ __hip_bfloat16 As[128 * 32];
  __shared__ __hip_bfloat16 Bs[128 * 32];
  const int t = threadIdx.x, w = t >> 6, l = t & 63;
  const int n0 = blockIdx.x * 128, m0 = blockIdx.y * 128;
  const int wm = w & 1, wn = w >> 1;
  f32x4 acc[4][4] = {};
  const int srow_b = (l >> 2);
  const int scol = (l & 3) * 8;
  for (int kt = 0; kt < 24; ++kt) {
    const int k0 = kt * 32;
#pragma unroll
    for (int j = 0; j < 2; ++j) {
      const int ldso = (w * 2 + j) * 512;
      const int row = (w * 2 + j) * 16 + srow_b;
      gl_lds16(&A[(size_t)(m0 + row) * 768 + k0 + scol], &As[ldso]);
      gl_lds16(&B[(size_t)(n0 + row) * 768 + k0 + scol], &Bs[ldso]);
    }
    __syncthreads();
    bf16x8 af[4], bfr[4];
#pragma unroll
    for (int mt = 0; mt < 4; ++mt)
      af[mt] = *(const bf16x8*)&As[(wm * 64 + mt * 16 + (l & 15)) * 32 + (l >> 4) * 8];
#pragma unroll
    for (int nt = 0; nt < 4; ++nt)
      bfr[nt] = *(const bf16x8*)&Bs[(wn * 64 + nt * 16 + (l & 15)) * 32 + (l >> 4) * 8];
#pragma unroll
    for (int mt = 0; mt < 4; ++mt)
#pragma unroll
      for (int nt = 0; nt < 4; ++nt)
        acc[mt][nt] = __builtin_amdgcn_mfma_f32_16x16x32_bf16(af[mt], bfr[nt], acc[mt][nt], 0, 0, 0);
    __syncthreads();
  }
#pragma unroll
  for (int nt = 0; nt < 4; ++nt) {
    const int col = n0 + wn * 64 + nt * 16 + (l & 15);
    const float bv = bias[col];
#pragma unroll
    for (int mt = 0; mt < 4; ++mt) {
      const int rbase = m0 + wm * 64 + mt * 16 + (l >> 4) * 4;
#pragma unroll
      for (int r = 0; r < 4; ++r)
        C[(size_t)(rbase + r) * 768 + col] = acc[mt][nt][r] + bv;
    }
  }
}

extern "C" void kernel_launch(void* const* d_in, const int* in_sizes, int n_in,
                              void* d_out, int out_size, void* d_ws, size_t ws_size,
                              hipStream_t stream) {
  const float* x      = (const float*)d_in[0];  // [8,4096,768]
  const float* qkv_w  = (const float*)d_in[1];  // [2304,768]
  const float* proj_w = (const float*)d_in[2];  // [768,768]
  const float* proj_b = (const float*)d_in[3];  // [768]
  float* out = (float*)d_out;                   // [8,4096,768] fp32

  char* ws = (char*)d_ws;
  const size_t MB_BYTES = (size_t)768 * 768 * 2;        // 1,179,648
  const size_t ARR_BYTES = (size_t)8 * 4096 * 768 * 2;  // 50,331,648
  __hip_bfloat16* Mb = (__hip_bfloat16*)ws;
  __hip_bfloat16* Ar = (__hip_bfloat16*)(ws + MB_BYTES);
  __hip_bfloat16* Ai = (__hip_bfloat16*)(ws + MB_BYTES + ARR_BYTES);
  __hip_bfloat16* Xf = (__hip_bfloat16*)(ws + MB_BYTES + 2 * ARR_BYTES);

  precompute_m<<<dim3(24, 24), 256, 0, stream>>>(proj_w, qkv_w, Mb);
  fft_a_mfma<<<dim3(6, 512), 256, 0, stream>>>(x, Ar, Ai);
  fft_b_mfma<<<dim3(6, 512), 256, 0, stream>>>(Ar, Ai, Xf);
  gemm_bt<<<dim3(6, 256), 256, 0, stream>>>(Xf, Mb, proj_b, out);
}

// Round 3
// 310.248 us; speedup vs baseline: 53.0901x; 1.0568x over previous
//
#include <hip/hip_runtime.h>
#include <hip/hip_bf16.h>

// B=8, N=4096 (=64x64 spatial), C=768.
// Y = ReFFT2_spatial(X) @ (proj_w @ Wv)^T + proj_b,  Wv = qkv_w[1536:2304].
// ReFFT2 via two MFMA twiddle passes; Hermitian symmetry: only k2=0..32 slabs
// materialized, pass B emits k2 and 64-k2 from shared accC/accS.

typedef __bf16 bf16x8 __attribute__((ext_vector_type(8)));
typedef __bf16 bf16x4 __attribute__((ext_vector_type(4)));
typedef float f32x4 __attribute__((ext_vector_type(4)));
typedef unsigned short ushort_t;
typedef unsigned int uint_t;

typedef __attribute__((address_space(3))) unsigned int lds_u32;
typedef __attribute__((address_space(1))) unsigned int glob_u32;

__device__ __forceinline__ void gl_lds16(const void* g, void* l) {
  __builtin_amdgcn_global_load_lds((const glob_u32*)g, (lds_u32*)l, 16, 0, 0);
}

__device__ __forceinline__ ushort_t f2bf(float f) {
  union { __hip_bfloat16 h; ushort_t s; } cv;
  cv.h = __float2bfloat16(f);
  return cv.s;
}

__device__ __forceinline__ bf16x8 ld_frag(const ushort_t* p) {
  union { bf16x8 v; bf16x4 h[2]; } r;
  r.h[0] = *(const bf16x4*)p;
  r.h[1] = *(const bf16x4*)(p + 4);
  return r.v;
}

// Twiddle A-fragment: val[j] = sign * trig(2*pi*(m*(k0+j) mod 64)/64), bf16.
__device__ __forceinline__ bf16x8 tw_frag(int m, int k0, bool use_sin, float sign) {
  union { bf16x8 v; ushort_t u[8]; } r;
#pragma unroll
  for (int j = 0; j < 8; ++j) {
    int ph = (m * (k0 + j)) & 63;
    float a = (float)ph * 0.09817477042468104f;  // 2*pi/64
    float x = use_sin ? __sinf(a) : __cosf(a);
    r.u[j] = f2bf(sign * x);
  }
  return r.v;
}

// ---------- K1: M[i,c] = sum_d P[i,d] * Q[1536+d, c]  (bf16 MFMA, bf16 out) ----------
// 128x128 tile, BK=32, grid 6x6. As[i][d] stride 40, Bs[c][d] stride 36 (transposed stage).
__global__ __launch_bounds__(256) void precompute_mfma(const float* __restrict__ P,
                                                       const float* __restrict__ Q,
                                                       __hip_bfloat16* __restrict__ Mb) {
  __shared__ ushort_t As[128 * 40];
  __shared__ ushort_t Bs[128 * 36];
  const int t = threadIdx.x;
  const int i0 = blockIdx.y * 128, c0 = blockIdx.x * 128;
  const int w = t >> 6, l = t & 63;
  const int wm = w & 1, wn = w >> 1;
  const int lm = l & 15, lq = l >> 4;
  f32x4 acc[4][4] = {};
  for (int kt = 0; kt < 24; ++kt) {
    const int k0 = kt * 32;
    {  // As: P rows, direct copy fp32->bf16, 16 d/thread
      int e = t * 16, row = e >> 5, dc = e & 16;
      const float* src = &P[(size_t)(i0 + row) * 768 + k0 + dc];
      float4 f0 = *(const float4*)&src[0], f1 = *(const float4*)&src[4];
      float4 f2 = *(const float4*)&src[8], f3 = *(const float4*)&src[12];
      union { ushort_t u[8]; uint4 v; } pk0, pk1;
      pk0.u[0] = f2bf(f0.x); pk0.u[1] = f2bf(f0.y); pk0.u[2] = f2bf(f0.z); pk0.u[3] = f2bf(f0.w);
      pk0.u[4] = f2bf(f1.x); pk0.u[5] = f2bf(f1.y); pk0.u[6] = f2bf(f1.z); pk0.u[7] = f2bf(f1.w);
      pk1.u[0] = f2bf(f2.x); pk1.u[1] = f2bf(f2.y); pk1.u[2] = f2bf(f2.z); pk1.u[3] = f2bf(f2.w);
      pk1.u[4] = f2bf(f3.x); pk1.u[5] = f2bf(f3.y); pk1.u[6] = f2bf(f3.z); pk1.u[7] = f2bf(f3.w);
      *(uint4*)&As[row * 40 + dc] = pk0.v;
      *(uint4*)&As[row * 40 + dc + 8] = pk1.v;
    }
#pragma unroll
    for (int it = 0; it < 8; ++it) {  // Bs: transposed stage of Q
      int p = it * 256 + t, c = p & 127, pr = p >> 7;  // pr 0..15 (d-pairs)
      float a = Q[(size_t)(1536 + k0 + 2 * pr) * 768 + c0 + c];
      float b = Q[(size_t)(1536 + k0 + 2 * pr + 1) * 768 + c0 + c];
      union { ushort_t u[2]; uint_t w_; } pk;
      pk.u[0] = f2bf(a); pk.u[1] = f2bf(b);
      *(uint_t*)&Bs[c * 36 + 2 * pr] = pk.w_;
    }
    __syncthreads();
    bf16x8 af[4], bfr[4];
#pragma unroll
    for (int mt = 0; mt < 4; ++mt)
      af[mt] = ld_frag(&As[(wm * 64 + mt * 16 + lm) * 40 + lq * 8]);
#pragma unroll
    for (int nt = 0; nt < 4; ++nt)
      bfr[nt] = ld_frag(&Bs[(wn * 64 + nt * 16 + lm) * 36 + lq * 8]);
#pragma unroll
    for (int mt = 0; mt < 4; ++mt)
#pragma unroll
      for (int nt = 0; nt < 4; ++nt)
        acc[mt][nt] = __builtin_amdgcn_mfma_f32_16x16x32_bf16(af[mt], bfr[nt], acc[mt][nt], 0, 0, 0);
    __syncthreads();
  }
#pragma unroll
  for (int nt = 0; nt < 4; ++nt) {
    const int col = c0 + wn * 64 + nt * 16 + lm;
#pragma unroll
    for (int mt = 0; mt < 4; ++mt) {
      const int rbase = i0 + wm * 64 + mt * 16 + lq * 4;
#pragma unroll
      for (int r = 0; r < 4; ++r)
        Mb[(size_t)(rbase + r) * 768 + col] = __float2bfloat16(acc[mt][nt][r]);
    }
  }
}

// ---------- K2: pass A (MFMA), contract n2. Store only k2=0..32 (Hermitian). ----------
// 4 waves, wave w covers 32 c-cols; 3 m-tiles (rows 0..47), store rows 0..32.
__global__ __launch_bounds__(256) void fft_a_mfma(const float* __restrict__ X,
                                                  __hip_bfloat16* __restrict__ Ar,
                                                  __hip_bfloat16* __restrict__ Ai) {
  __shared__ ushort_t Xs[128 * 68];   // [c][n2]
  __shared__ ushort_t Ep[48 * 136];   // [k2][c]
  const int t = threadIdx.x;
  const int s = blockIdx.y;           // b*64 + n1
  const int c0 = blockIdx.x * 128;
  const float* src = X + (size_t)s * 64 * 768 + c0;
#pragma unroll
  for (int it = 0; it < 16; ++it) {
    int p = it * 256 + t;
    int c = p & 127, pr = p >> 7;     // n2 pair
    float a = src[(size_t)(2 * pr) * 768 + c];
    float b = src[(size_t)(2 * pr + 1) * 768 + c];
    union { ushort_t u[2]; uint_t w_; } pk;
    pk.u[0] = f2bf(a); pk.u[1] = f2bf(b);
    *(uint_t*)&Xs[c * 68 + 2 * pr] = pk.w_;
  }
  __syncthreads();
  const int w = t >> 6, l = t & 63;
  const int lm = l & 15, lq = l >> 4;
  bf16x8 afc[3][2], afs[3][2];
#pragma unroll
  for (int mt = 0; mt < 3; ++mt)
#pragma unroll
    for (int ks = 0; ks < 2; ++ks) {
      int m = mt * 16 + lm;           // k2 row 0..47
      int k0 = ks * 32 + lq * 8;
      afc[mt][ks] = tw_frag(m, k0, false, 1.f);
      afs[mt][ks] = tw_frag(m, k0, true, 1.f);
    }
  f32x4 accr[3][2] = {}, acci[3][2] = {};
#pragma unroll
  for (int ks = 0; ks < 2; ++ks) {
    bf16x8 bf[2];
#pragma unroll
    for (int nt = 0; nt < 2; ++nt) {
      int c = w * 32 + nt * 16 + lm;
      bf[nt] = ld_frag(&Xs[c * 68 + ks * 32 + lq * 8]);
    }
#pragma unroll
    for (int mt = 0; mt < 3; ++mt)
#pragma unroll
      for (int nt = 0; nt < 2; ++nt) {
        accr[mt][nt] = __builtin_amdgcn_mfma_f32_16x16x32_bf16(afc[mt][ks], bf[nt], accr[mt][nt], 0, 0, 0);
        acci[mt][nt] = __builtin_amdgcn_mfma_f32_16x16x32_bf16(afs[mt][ks], bf[nt], acci[mt][nt], 0, 0, 0);
      }
  }
#pragma unroll
  for (int arr = 0; arr < 2; ++arr) {
    __syncthreads();
#pragma unroll
    for (int mt = 0; mt < 3; ++mt)
#pragma unroll
      for (int nt = 0; nt < 2; ++nt)
#pragma unroll
        for (int r = 0; r < 4; ++r) {
          int row = mt * 16 + lq * 4 + r;
          int col = w * 32 + nt * 16 + lm;
          float v = arr ? acci[mt][nt][r] : accr[mt][nt][r];
          Ep[row * 136 + col] = f2bf(v);
        }
    __syncthreads();
    __hip_bfloat16* dst = arr ? Ai : Ar;
#pragma unroll
    for (int it = 0; it < 3; ++it) {
      int idx = it * 256 + t;          // uint4 units; rows 0..47, keep <=32
      int row = idx >> 4, cq = (idx & 15) * 8;
      if (row <= 32) {
        uint4 v = *(const uint4*)&Ep[row * 136 + cq];
        *(uint4*)&dst[(size_t)(s * 64 + row) * 768 + c0 + cq] = v;
      }
    }
  }
}

// ---------- K3: pass B (MFMA), contract n1. Pair outputs k2 / 64-k2. ----------
__global__ __launch_bounds__(256) void fft_b_mfma(const __hip_bfloat16* __restrict__ Ar,
                                                  const __hip_bfloat16* __restrict__ Ai,
                                                  __hip_bfloat16* __restrict__ Xf) {
  __shared__ ushort_t Rs[128 * 68], Is[128 * 68];
  __shared__ ushort_t Ep[64 * 136];
  const int t = threadIdx.x;
  const int bz = blockIdx.y;          // b*33 + k2
  const int b = bz / 33, k2 = bz % 33;
  const int c0 = blockIdx.x * 128;
  const ushort_t* ar = (const ushort_t*)Ar + ((size_t)(b * 64) * 64 + k2) * 768 + c0;
  const ushort_t* ai = (const ushort_t*)Ai + ((size_t)(b * 64) * 64 + k2) * 768 + c0;
  const size_t n1s = (size_t)64 * 768;
#pragma unroll
  for (int it = 0; it < 16; ++it) {
    int p = it * 256 + t;
    int c = p & 127, pr = p >> 7;
    size_t o0 = (size_t)(2 * pr) * n1s + c;
    size_t o1 = o0 + n1s;
    union { ushort_t u[2]; uint_t w_; } p1, p2;
    p1.u[0] = ar[o0]; p1.u[1] = ar[o1];
    p2.u[0] = ai[o0]; p2.u[1] = ai[o1];
    *(uint_t*)&Rs[c * 68 + 2 * pr] = p1.w_;
    *(uint_t*)&Is[c * 68 + 2 * pr] = p2.w_;
  }
  __syncthreads();
  const int w = t >> 6, l = t & 63;
  const int wm = w & 1, wn = w >> 1;
  const int lm = l & 15, lq = l >> 4;
  bf16x8 afc[2][2], afs[2][2];
#pragma unroll
  for (int mt = 0; mt < 2; ++mt)
#pragma unroll
    for (int ks = 0; ks < 2; ++ks) {
      int m = wm * 32 + mt * 16 + lm;   // k1
      int k0 = ks * 32 + lq * 8;        // n1
      afc[mt][ks] = tw_frag(m, k0, false, 1.f);
      afs[mt][ks] = tw_frag(m, k0, true, 1.f);    // +sin
    }
  f32x4 accC[2][4] = {}, accS[2][4] = {};
#pragma unroll
  for (int ks = 0; ks < 2; ++ks) {
    bf16x8 bR[4], bI[4];
#pragma unroll
    for (int nt = 0; nt < 4; ++nt) {
      int c = wn * 64 + nt * 16 + lm;
      int kb = ks * 32 + lq * 8;
      bR[nt] = ld_frag(&Rs[c * 68 + kb]);
      bI[nt] = ld_frag(&Is[c * 68 + kb]);
    }
#pragma unroll
    for (int mt = 0; mt < 2; ++mt)
#pragma unroll
      for (int nt = 0; nt < 4; ++nt) {
        accC[mt][nt] = __builtin_amdgcn_mfma_f32_16x16x32_bf16(afc[mt][ks], bR[nt], accC[mt][nt], 0, 0, 0);
        accS[mt][nt] = __builtin_amdgcn_mfma_f32_16x16x32_bf16(afs[mt][ks], bI[nt], accS[mt][nt], 0, 0, 0);
      }
  }
  // out(k2) = accC - accS ; out(64-k2) = accC + accS (k2 in 1..31)
  const int nout = (k2 >= 1 && k2 <= 31) ? 2 : 1;
  for (int o = 0; o < nout; ++o) {
    __syncthreads();
#pragma unroll
    for (int mt = 0; mt < 2; ++mt)
#pragma unroll
      for (int nt = 0; nt < 4; ++nt)
#pragma unroll
        for (int r = 0; r < 4; ++r) {
          int row = wm * 32 + mt * 16 + lq * 4 + r;   // k1
          int col = wn * 64 + nt * 16 + lm;           // c
          float v = o ? (accC[mt][nt][r] + accS[mt][nt][r])
                      : (accC[mt][nt][r] - accS[mt][nt][r]);
          Ep[row * 136 + col] = f2bf(v);
        }
    __syncthreads();
    const int k2o = o ? (64 - k2) : k2;
#pragma unroll
    for (int it = 0; it < 4; ++it) {
      int idx = it * 256 + t;
      int k1 = idx >> 4, cq = (idx & 15) * 8;
      uint4 v = *(const uint4*)&Ep[k1 * 136 + cq];
      *(uint4*)&Xf[((size_t)b * 4096 + k1 * 64 + k2o) * 768 + c0 + cq] = v;
    }
  }
}

// ---------- K4: Y[m,n] = sum_k Xf[m,k]*Mb[n,k] + bias[n]  (bf16 MFMA, fp32 out) ----------
__global__ __launch_bounds__(256) void gemm_bt(const __hip_bfloat16* __restrict__ A,
                                               const __hip_bfloat16* __restrict__ B,
                                               const float* __restrict__ bias,
                                               float* __restrict__ C) {
  __shared__ __hip_bfloat16 As[128 * 32];
  __shared__ __hip_bfloat16 Bs[128 * 32];
  const int t = threadIdx.x, w = t >> 6, l = t & 63;
  // XCD swizzle: the 6 n-tiles sharing an m-tile's A panel land on one XCD.
  const int L = blockIdx.x + blockIdx.y * 6;
  const int s = L >> 3, xcd = L & 7;
  const int n0 = (s % 6) * 128;
  const int m0 = ((s / 6) * 8 + xcd) * 128;
  const int wm = w & 1, wn = w >> 1;
  f32x4 acc[4][4] = {};
  const int srow_b = (l >> 2);
  const int scol = (l & 3) * 8;
  for (int kt = 0; kt < 24; ++kt) {
    const int k0 = kt * 32;
#pragma unroll
    for (int j = 0; j < 2; ++j) {
      const int ldso = (w * 2 + j) * 512;
      const int row = (w * 2 + j) * 16 + srow_b;
      gl_lds16(&A[(size_t)(m0 + row) * 768 + k0 + scol], &As[ldso]);
      gl_lds16(&B[(size_t)(n0 + row) * 768 + k0 + scol], &Bs[ldso]);
    }
    __syncthreads();
    bf16x8 af[4], bfr[4];
#pragma unroll
    for (int mt = 0; mt < 4; ++mt)
      af[mt] = *(const bf16x8*)&As[(wm * 64 + mt * 16 + (l & 15)) * 32 + (l >> 4) * 8];
#pragma unroll
    for (int nt = 0; nt < 4; ++nt)
      bfr[nt] = *(const bf16x8*)&Bs[(wn * 64 + nt * 16 + (l & 15)) * 32 + (l >> 4) * 8];
#pragma unroll
    for (int mt = 0; mt < 4; ++mt)
#pragma unroll
      for (int nt = 0; nt < 4; ++nt)
        acc[mt][nt] = __builtin_amdgcn_mfma_f32_16x16x32_bf16(af[mt], bfr[nt], acc[mt][nt], 0, 0, 0);
    __syncthreads();
  }
#pragma unroll
  for (int nt = 0; nt < 4; ++nt) {
    const int col = n0 + wn * 64 + nt * 16 + (l & 15);
    const float bv = bias[col];
#pragma unroll
    for (int mt = 0; mt < 4; ++mt) {
      const int rbase = m0 + wm * 64 + mt * 16 + (l >> 4) * 4;
#pragma unroll
      for (int r = 0; r < 4; ++r)
        C[(size_t)(rbase + r) * 768 + col] = acc[mt][nt][r] + bv;
    }
  }
}

extern "C" void kernel_launch(void* const* d_in, const int* in_sizes, int n_in,
                              void* d_out, int out_size, void* d_ws, size_t ws_size,
                              hipStream_t stream) {
  const float* x      = (const float*)d_in[0];  // [8,4096,768]
  const float* qkv_w  = (const float*)d_in[1];  // [2304,768]
  const float* proj_w = (const float*)d_in[2];  // [768,768]
  const float* proj_b = (const float*)d_in[3];  // [768]
  float* out = (float*)d_out;                   // [8,4096,768] fp32

  char* ws = (char*)d_ws;
  const size_t MB_BYTES = (size_t)768 * 768 * 2;
  const size_t ARR_BYTES = (size_t)8 * 4096 * 768 * 2;
  __hip_bfloat16* Mb = (__hip_bfloat16*)ws;
  __hip_bfloat16* Ar = (__hip_bfloat16*)(ws + MB_BYTES);
  __hip_bfloat16* Ai = (__hip_bfloat16*)(ws + MB_BYTES + ARR_BYTES);
  __hip_bfloat16* Xf = (__hip_bfloat16*)(ws + MB_BYTES + 2 * ARR_BYTES);

  precompute_mfma<<<dim3(6, 6), 256, 0, stream>>>(proj_w, qkv_w, Mb);
  fft_a_mfma<<<dim3(6, 512), 256, 0, stream>>>(x, Ar, Ai);
  fft_b_mfma<<<dim3(6, 264), 256, 0, stream>>>(Ar, Ai, Xf);
  gemm_bt<<<dim3(6, 256), 256, 0, stream>>>(Xf, Mb, proj_b, out);
}

// Round 4
// 280.577 us; speedup vs baseline: 58.7044x; 1.1058x over previous
//
#include <hip/hip_runtime.h>
#include <hip/hip_bf16.h>

// B=8, N=4096 (=64x64 spatial), C=768.
// Y = ReFFT2_spatial(X) @ (proj_w @ Wv)^T + proj_b,  Wv = qkv_w[1536:2304].
// K1 (merged into K2's grid): M = proj_w @ Wv  (bf16)
// K2: pass A twiddle-MFMA, Hermitian store k2=0..32
// K3: pass B twiddle-MFMA, emits k2 and 64-k2
// K4: Y = Xf @ M^T + b   (32x32x16 MFMA, BK=64, XOR-swizzled staging)

typedef __bf16 bf16x8 __attribute__((ext_vector_type(8)));
typedef __bf16 bf16x4 __attribute__((ext_vector_type(4)));
typedef float f32x4 __attribute__((ext_vector_type(4)));
typedef float f32x16 __attribute__((ext_vector_type(16)));
typedef unsigned short ushort_t;
typedef unsigned int uint_t;

typedef __attribute__((address_space(3))) unsigned int lds_u32;
typedef __attribute__((address_space(1))) unsigned int glob_u32;

__device__ __forceinline__ void gl_lds16(const void* g, void* l) {
  __builtin_amdgcn_global_load_lds((const glob_u32*)g, (lds_u32*)l, 16, 0, 0);
}

__device__ __forceinline__ ushort_t f2bf(float f) {
  union { __hip_bfloat16 h; ushort_t s; } cv;
  cv.h = __float2bfloat16(f);
  return cv.s;
}

__device__ __forceinline__ bf16x8 ld_frag(const ushort_t* p) {  // 8B-aligned
  union { bf16x8 v; bf16x4 h[2]; } r;
  r.h[0] = *(const bf16x4*)p;
  r.h[1] = *(const bf16x4*)(p + 4);
  return r.v;
}

// Twiddle A-fragment: val[j] = sign * trig(2*pi*(m*(k0+j) mod 64)/64), bf16.
__device__ __forceinline__ bf16x8 tw_frag(int m, int k0, bool use_sin, float sign) {
  union { bf16x8 v; ushort_t u[8]; } r;
#pragma unroll
  for (int j = 0; j < 8; ++j) {
    int ph = (m * (k0 + j)) & 63;
    float a = (float)ph * 0.09817477042468104f;  // 2*pi/64
    float x = use_sin ? __sinf(a) : __cosf(a);
    r.u[j] = f2bf(sign * x);
  }
  return r.v;
}

// ---------- K2 (+K1): pass A over by<512; precompute M over by>=512 ----------
__global__ __launch_bounds__(256) void fft_a_pre(const float* __restrict__ X,
                                                 const float* __restrict__ P,
                                                 const float* __restrict__ Q,
                                                 __hip_bfloat16* __restrict__ Ar,
                                                 __hip_bfloat16* __restrict__ Ai,
                                                 __hip_bfloat16* __restrict__ Mb) {
  __shared__ ushort_t smem[9728];     // 19456 B; both paths overlay into this
  const int t = threadIdx.x;
  const int c0 = blockIdx.x * 128;
  const int w = t >> 6, l = t & 63;
  const int lm = l & 15, lq = l >> 4;

  if (blockIdx.y < 512) {             // ---------------- FFT pass A ----------------
    ushort_t* Xs = smem;              // [c][n2] stride 68 (8704 ush)
    ushort_t* Ep = smem;              // [k2][c] stride 136 (6528 ush) — overlays Xs after use
    const int s = blockIdx.y;         // b*64 + n1
    const float* src = X + (size_t)s * 64 * 768 + c0;
#pragma unroll
    for (int it = 0; it < 16; ++it) {
      int p = it * 256 + t;
      int c = p & 127, pr = p >> 7;   // n2 pair
      float a = src[(size_t)(2 * pr) * 768 + c];
      float b = src[(size_t)(2 * pr + 1) * 768 + c];
      union { ushort_t u[2]; uint_t w_; } pk;
      pk.u[0] = f2bf(a); pk.u[1] = f2bf(b);
      *(uint_t*)&Xs[c * 68 + 2 * pr] = pk.w_;
    }
    __syncthreads();
    bf16x8 afc[3][2], afs[3][2];
#pragma unroll
    for (int mt = 0; mt < 3; ++mt)
#pragma unroll
      for (int ks = 0; ks < 2; ++ks) {
        int m = mt * 16 + lm;         // k2 row 0..47
        int k0 = ks * 32 + lq * 8;
        afc[mt][ks] = tw_frag(m, k0, false, 1.f);
        afs[mt][ks] = tw_frag(m, k0, true, 1.f);
      }
    f32x4 accr[3][2] = {}, acci[3][2] = {};
#pragma unroll
    for (int ks = 0; ks < 2; ++ks) {
      bf16x8 bf[2];
#pragma unroll
      for (int nt = 0; nt < 2; ++nt) {
        int c = w * 32 + nt * 16 + lm;
        bf[nt] = ld_frag(&Xs[c * 68 + ks * 32 + lq * 8]);
      }
#pragma unroll
      for (int mt = 0; mt < 3; ++mt)
#pragma unroll
        for (int nt = 0; nt < 2; ++nt) {
          accr[mt][nt] = __builtin_amdgcn_mfma_f32_16x16x32_bf16(afc[mt][ks], bf[nt], accr[mt][nt], 0, 0, 0);
          acci[mt][nt] = __builtin_amdgcn_mfma_f32_16x16x32_bf16(afs[mt][ks], bf[nt], acci[mt][nt], 0, 0, 0);
        }
    }
#pragma unroll
    for (int arr = 0; arr < 2; ++arr) {
      __syncthreads();                // Xs dead after this point on arr=0
#pragma unroll
      for (int mt = 0; mt < 3; ++mt)
#pragma unroll
        for (int nt = 0; nt < 2; ++nt)
#pragma unroll
          for (int r = 0; r < 4; ++r) {
            int row = mt * 16 + lq * 4 + r;
            int col = w * 32 + nt * 16 + lm;
            float v = arr ? acci[mt][nt][r] : accr[mt][nt][r];
            Ep[row * 136 + col] = f2bf(v);
          }
      __syncthreads();
      __hip_bfloat16* dst = arr ? Ai : Ar;
#pragma unroll
      for (int it = 0; it < 3; ++it) {
        int idx = it * 256 + t;       // uint4 units; keep rows <=32
        int row = idx >> 4, cq = (idx & 15) * 8;
        if (row <= 32) {
          uint4 v = *(const uint4*)&Ep[row * 136 + cq];
          *(uint4*)&dst[(size_t)(s * 64 + row) * 768 + c0 + cq] = v;
        }
      }
    }
  } else {                            // ---------------- precompute M ----------------
    ushort_t* As = smem;              // [i][d] stride 40 (5120 ush)
    ushort_t* Bs = smem + 5120;       // [c][d] stride 36 (4608 ush)
    const int i0 = (blockIdx.y - 512) * 128;
    const int wm = w & 1, wn = w >> 1;
    f32x4 acc[4][4] = {};
    for (int kt = 0; kt < 24; ++kt) {
      const int k0 = kt * 32;
      {
        int e = t * 16, row = e >> 5, dc = e & 16;
        const float* src = &P[(size_t)(i0 + row) * 768 + k0 + dc];
        float4 f0 = *(const float4*)&src[0], f1 = *(const float4*)&src[4];
        float4 f2 = *(const float4*)&src[8], f3 = *(const float4*)&src[12];
        union { ushort_t u[8]; uint4 v; } pk0, pk1;
        pk0.u[0] = f2bf(f0.x); pk0.u[1] = f2bf(f0.y); pk0.u[2] = f2bf(f0.z); pk0.u[3] = f2bf(f0.w);
        pk0.u[4] = f2bf(f1.x); pk0.u[5] = f2bf(f1.y); pk0.u[6] = f2bf(f1.z); pk0.u[7] = f2bf(f1.w);
        pk1.u[0] = f2bf(f2.x); pk1.u[1] = f2bf(f2.y); pk1.u[2] = f2bf(f2.z); pk1.u[3] = f2bf(f2.w);
        pk1.u[4] = f2bf(f3.x); pk1.u[5] = f2bf(f3.y); pk1.u[6] = f2bf(f3.z); pk1.u[7] = f2bf(f3.w);
        *(uint4*)&As[row * 40 + dc] = pk0.v;
        *(uint4*)&As[row * 40 + dc + 8] = pk1.v;
      }
#pragma unroll
      for (int it = 0; it < 8; ++it) {
        int p = it * 256 + t, c = p & 127, pr = p >> 7;
        float a = Q[(size_t)(1536 + k0 + 2 * pr) * 768 + c0 + c];
        float b = Q[(size_t)(1536 + k0 + 2 * pr + 1) * 768 + c0 + c];
        union { ushort_t u[2]; uint_t w_; } pk;
        pk.u[0] = f2bf(a); pk.u[1] = f2bf(b);
        *(uint_t*)&Bs[c * 36 + 2 * pr] = pk.w_;
      }
      __syncthreads();
      bf16x8 af[4], bfr[4];
#pragma unroll
      for (int mt = 0; mt < 4; ++mt)
        af[mt] = ld_frag(&As[(wm * 64 + mt * 16 + lm) * 40 + lq * 8]);
#pragma unroll
      for (int nt = 0; nt < 4; ++nt)
        bfr[nt] = ld_frag(&Bs[(wn * 64 + nt * 16 + lm) * 36 + lq * 8]);
#pragma unroll
      for (int mt = 0; mt < 4; ++mt)
#pragma unroll
        for (int nt = 0; nt < 4; ++nt)
          acc[mt][nt] = __builtin_amdgcn_mfma_f32_16x16x32_bf16(af[mt], bfr[nt], acc[mt][nt], 0, 0, 0);
      __syncthreads();
    }
#pragma unroll
    for (int nt = 0; nt < 4; ++nt) {
      const int col = c0 + wn * 64 + nt * 16 + lm;
#pragma unroll
      for (int mt = 0; mt < 4; ++mt) {
        const int rbase = i0 + wm * 64 + mt * 16 + lq * 4;
#pragma unroll
        for (int r = 0; r < 4; ++r)
          Mb[(size_t)(rbase + r) * 768 + col] = __float2bfloat16(acc[mt][nt][r]);
      }
    }
  }
}

// ---------- K3: pass B (MFMA), contract n1. Pair outputs k2 / 64-k2. ----------
__global__ __launch_bounds__(256) void fft_b_mfma(const __hip_bfloat16* __restrict__ Ar,
                                                  const __hip_bfloat16* __restrict__ Ai,
                                                  __hip_bfloat16* __restrict__ Xf) {
  __shared__ ushort_t smem[17408];    // Rs 8704 | Is 8704 ; Ep overlays Rs
  ushort_t* Rs = smem;
  ushort_t* Is = smem + 8704;
  ushort_t* Ep = smem;                // [k1][c] stride 136, used after Rs dead
  const int t = threadIdx.x;
  const int bz = blockIdx.y;          // b*33 + k2
  const int b = bz / 33, k2 = bz % 33;
  const int c0 = blockIdx.x * 128;
  const ushort_t* ar = (const ushort_t*)Ar + ((size_t)(b * 64) * 64 + k2) * 768 + c0;
  const ushort_t* ai = (const ushort_t*)Ai + ((size_t)(b * 64) * 64 + k2) * 768 + c0;
  const size_t n1s = (size_t)64 * 768;
#pragma unroll
  for (int it = 0; it < 16; ++it) {
    int p = it * 256 + t;
    int c = p & 127, pr = p >> 7;
    size_t o0 = (size_t)(2 * pr) * n1s + c;
    size_t o1 = o0 + n1s;
    union { ushort_t u[2]; uint_t w_; } p1, p2;
    p1.u[0] = ar[o0]; p1.u[1] = ar[o1];
    p2.u[0] = ai[o0]; p2.u[1] = ai[o1];
    *(uint_t*)&Rs[c * 68 + 2 * pr] = p1.w_;
    *(uint_t*)&Is[c * 68 + 2 * pr] = p2.w_;
  }
  __syncthreads();
  const int w = t >> 6, l = t & 63;
  const int wm = w & 1, wn = w >> 1;
  const int lm = l & 15, lq = l >> 4;
  bf16x8 afc[2][2], afs[2][2];
#pragma unroll
  for (int mt = 0; mt < 2; ++mt)
#pragma unroll
    for (int ks = 0; ks < 2; ++ks) {
      int m = wm * 32 + mt * 16 + lm;   // k1
      int k0 = ks * 32 + lq * 8;        // n1
      afc[mt][ks] = tw_frag(m, k0, false, 1.f);
      afs[mt][ks] = tw_frag(m, k0, true, 1.f);
    }
  f32x4 accC[2][4] = {}, accS[2][4] = {};
#pragma unroll
  for (int ks = 0; ks < 2; ++ks) {
    bf16x8 bR[4], bI[4];
#pragma unroll
    for (int nt = 0; nt < 4; ++nt) {
      int c = wn * 64 + nt * 16 + lm;
      int kb = ks * 32 + lq * 8;
      bR[nt] = ld_frag(&Rs[c * 68 + kb]);
      bI[nt] = ld_frag(&Is[c * 68 + kb]);
    }
#pragma unroll
    for (int mt = 0; mt < 2; ++mt)
#pragma unroll
      for (int nt = 0; nt < 4; ++nt) {
        accC[mt][nt] = __builtin_amdgcn_mfma_f32_16x16x32_bf16(afc[mt][ks], bR[nt], accC[mt][nt], 0, 0, 0);
        accS[mt][nt] = __builtin_amdgcn_mfma_f32_16x16x32_bf16(afs[mt][ks], bI[nt], accS[mt][nt], 0, 0, 0);
      }
  }
  const int nout = (k2 >= 1 && k2 <= 31) ? 2 : 1;
  for (int o = 0; o < nout; ++o) {
    __syncthreads();                   // Rs/Is dead from here
#pragma unroll
    for (int mt = 0; mt < 2; ++mt)
#pragma unroll
      for (int nt = 0; nt < 4; ++nt)
#pragma unroll
        for (int r = 0; r < 4; ++r) {
          int row = wm * 32 + mt * 16 + lq * 4 + r;   // k1
          int col = wn * 64 + nt * 16 + lm;           // c
          float v = o ? (accC[mt][nt][r] + accS[mt][nt][r])
                      : (accC[mt][nt][r] - accS[mt][nt][r]);
          Ep[row * 136 + col] = f2bf(v);
        }
    __syncthreads();
    const int k2o = o ? (64 - k2) : k2;
#pragma unroll
    for (int it = 0; it < 4; ++it) {
      int idx = it * 256 + t;
      int k1 = idx >> 4, cq = (idx & 15) * 8;
      uint4 v = *(const uint4*)&Ep[k1 * 136 + cq];
      *(uint4*)&Xf[((size_t)b * 4096 + k1 * 64 + k2o) * 768 + c0 + cq] = v;
    }
  }
}

// ---------- K4: Y[m,n] = sum_k Xf[m,k]*Mb[n,k] + bias[n] ----------
// 128x128 tile, BK=64, 32x32x16 MFMA, XOR-swizzled global_load_lds staging.
__global__ __launch_bounds__(256) void gemm_bt(const __hip_bfloat16* __restrict__ A,
                                               const __hip_bfloat16* __restrict__ B,
                                               const float* __restrict__ bias,
                                               float* __restrict__ C) {
  __shared__ ushort_t As[128 * 64];
  __shared__ ushort_t Bs[128 * 64];
  const int t = threadIdx.x, w = t >> 6, l = t & 63;
  // XCD swizzle: 6 n-tiles sharing an A panel on one XCD (round-robin L%8).
  const int L = blockIdx.x + blockIdx.y * 6;
  const int s = L >> 3, xcd = L & 7;
  const int n0 = (s % 6) * 128;
  const int m0 = ((s / 6) * 8 + xcd) * 128;
  const int wm = w & 1, wn = w >> 1;
  f32x16 acc[2][2] = {};
  // staging lane constants: row-in-group, swizzled source chunk
  const int srow = l >> 3;                       // 0..7
  const int schunk = (l & 7) ^ srow;             // global 8-elem chunk
  const int lr = l & 31, lh = l >> 5;            // MFMA row / k-half
  for (int kt = 0; kt < 12; ++kt) {
    const int k0 = kt * 64;
#pragma unroll
    for (int i = 0; i < 4; ++i) {
      const int rbase = w * 32 + i * 8;          // wave-uniform
      const int row = rbase + srow;
      gl_lds16(&A[(size_t)(m0 + row) * 768 + k0 + schunk * 8], &As[rbase * 64]);
      gl_lds16(&B[(size_t)(n0 + row) * 768 + k0 + schunk * 8], &Bs[rbase * 64]);
    }
    __syncthreads();
#pragma unroll
    for (int ks = 0; ks < 4; ++ks) {
      bf16x8 af[2], bf[2];
#pragma unroll
      for (int mt = 0; mt < 2; ++mt) {
        int row = wm * 64 + mt * 32 + lr;
        int ch = (ks * 2 + lh) ^ (lr & 7);       // un-swizzle
        af[mt] = *(const bf16x8*)&As[row * 64 + ch * 8];
      }
#pragma unroll
      for (int nt = 0; nt < 2; ++nt) {
        int row = wn * 64 + nt * 32 + lr;
        int ch = (ks * 2 + lh) ^ (lr & 7);
        bf[nt] = *(const bf16x8*)&Bs[row * 64 + ch * 8];
      }
#pragma unroll
      for (int mt = 0; mt < 2; ++mt)
#pragma unroll
        for (int nt = 0; nt < 2; ++nt)
          acc[mt][nt] = __builtin_amdgcn_mfma_f32_32x32x16_bf16(af[mt], bf[nt], acc[mt][nt], 0, 0, 0);
    }
    __syncthreads();
  }
  // epilogue: C/D layout 32x32: col=lane&31, row=(reg&3)+8*(reg>>2)+4*(lane>>5)
#pragma unroll
  for (int nt = 0; nt < 2; ++nt) {
    const int col = n0 + wn * 64 + nt * 32 + lr;
    const float bv = bias[col];
#pragma unroll
    for (int mt = 0; mt < 2; ++mt) {
      const int rb = m0 + wm * 64 + mt * 32 + 4 * lh;
#pragma unroll
      for (int reg = 0; reg < 16; ++reg) {
        const int row = rb + (reg & 3) + 8 * (reg >> 2);
        C[(size_t)row * 768 + col] = acc[mt][nt][reg] + bv;
      }
    }
  }
}

extern "C" void kernel_launch(void* const* d_in, const int* in_sizes, int n_in,
                              void* d_out, int out_size, void* d_ws, size_t ws_size,
                              hipStream_t stream) {
  const float* x      = (const float*)d_in[0];  // [8,4096,768]
  const float* qkv_w  = (const float*)d_in[1];  // [2304,768]
  const float* proj_w = (const float*)d_in[2];  // [768,768]
  const float* proj_b = (const float*)d_in[3];  // [768]
  float* out = (float*)d_out;                   // [8,4096,768] fp32

  char* ws = (char*)d_ws;
  const size_t MB_BYTES = (size_t)768 * 768 * 2;
  const size_t ARR_BYTES = (size_t)8 * 4096 * 768 * 2;
  __hip_bfloat16* Mb = (__hip_bfloat16*)ws;
  __hip_bfloat16* Ar = (__hip_bfloat16*)(ws + MB_BYTES);
  __hip_bfloat16* Ai = (__hip_bfloat16*)(ws + MB_BYTES + ARR_BYTES);
  __hip_bfloat16* Xf = (__hip_bfloat16*)(ws + MB_BYTES + 2 * ARR_BYTES);

  fft_a_pre<<<dim3(6, 518), 256, 0, stream>>>(x, proj_w, qkv_w, Ar, Ai, Mb);
  fft_b_mfma<<<dim3(6, 264), 256, 0, stream>>>(Ar, Ai, Xf);
  gemm_bt<<<dim3(6, 256), 256, 0, stream>>>(Xf, Mb, proj_b, out);
}